// Round 11
// baseline (80.860 us; speedup 1.0000x reference)
//
#include <hip/hip_runtime.h>

#define NS 65536      // stocks
#define HID 512       // hidden
#define NE 128        // industries
#define NEG 0.01f     // LeakyReLU slope

typedef int   vi4 __attribute__((ext_vector_type(4)));
typedef float vf4 __attribute__((ext_vector_type(4)));

// ---------------------------------------------------------------------------
// K1: decode one-hot rows -> ind[s]. Nontemporal vi4 loads (single-use, 33.5 MB).
__global__ __launch_bounds__(1024) void k_find(const int* __restrict__ im,
                                               int* __restrict__ ind) {
    __shared__ int lind[256];
    const int b = blockIdx.x, t = threadIdx.x;
    const vi4* p = reinterpret_cast<const vi4*>(im) + (size_t)b * 8192;
#pragma unroll
    for (int j = t; j < 8192; j += 1024) {   // 256 rows x 32 vi4, 8 iters
        vi4 v = __builtin_nontemporal_load(p + j);
        int s = j >> 5;          // local row
        int c = (j & 31) << 2;   // column of v[0]
        if (v[0] == 1) lind[s] = c;
        if (v[1] == 1) lind[s] = c + 1;
        if (v[2] == 1) lind[s] = c + 2;
        if (v[3] == 1) lind[s] = c + 3;
    }
    __syncthreads();
    if (t < 256) ind[b * 256 + t] = lind[t];
}

// ---------------------------------------------------------------------------
// K2: per-industry row-sum with self-compaction. Block = (industry e, quarter q).
// Scan 16384 ind entries (L2-resident), compact matching stock ids into LDS,
// then gather-sum their e_s rows (nontemporal vf4). Writes disjoint
// partial[q][e][:] and counts[q][e]. No global atomics, no sorted array.
__global__ __launch_bounds__(1024) void k_agg(const float* __restrict__ e_s,
                                              const int* __restrict__ ind,
                                              float* __restrict__ partial,
                                              int* __restrict__ counts) {
    __shared__ int rows[1024];
    __shared__ vf4 red[1024];
    __shared__ int cntL;
    const int e = blockIdx.x >> 2;
    const int q = blockIdx.x & 3;
    const int t = threadIdx.x;
    if (t == 0) cntL = 0;
    __syncthreads();
    const int base = q * (NS / 4);
#pragma unroll
    for (int k = 0; k < (NS / 4) / 1024; ++k) {   // 16 coalesced L2 reads
        int idx = base + k * 1024 + t;
        if (ind[idx] == e) {
            int p = atomicAdd(&cntL, 1);          // LDS atomic append
            if (p < 1024) rows[p] = idx;
        }
    }
    __syncthreads();
    const int cnt = (cntL < 1024) ? cntL : 1024;  // ~128 expected
    const int g = t >> 7;        // 8 row-groups
    const int l = t & 127;       // vf4 column
    vf4 acc = {0.f, 0.f, 0.f, 0.f};
#pragma unroll 4
    for (int i = g; i < cnt; i += 8) {
        int row = rows[i];       // wave-uniform broadcast
        vf4 v = __builtin_nontemporal_load(
            reinterpret_cast<const vf4*>(e_s + (size_t)row * HID) + l);
        acc += v;
    }
    red[t] = acc;
    __syncthreads();
    if (g == 0) {
        vf4 a = red[l];
#pragma unroll
        for (int p = 1; p < 8; ++p) a += red[l + p * 128];
        reinterpret_cast<vf4*>(partial + ((size_t)(q * NE + e)) * HID)[l] = a;
    }
    if (t == 0) counts[q * NE + e] = cnt;
}

// ---------------------------------------------------------------------------
// K3: fused edge-GEMM + output stream with self-compaction.
// Block = (industry e, half h). Sum 4 partials -> GEMM (W L2-hot) -> build
// LeakyReLU row once in LDS -> scan+compact its half of ind -> stream 2KB
// rows with nontemporal stores.
__global__ __launch_bounds__(1024) void k_gemm_out(const float* __restrict__ partial,
                                                   const float* __restrict__ W,
                                                   const float* __restrict__ bias,
                                                   const int* __restrict__ ind,
                                                   const int* __restrict__ counts,
                                                   float* __restrict__ out) {
    __shared__ float aL[HID];
    __shared__ float redf[1024];
    __shared__ float rowL[HID];
    __shared__ int rows[1024];
    __shared__ int cntL;
    const int e = blockIdx.x >> 1;
    const int h = blockIdx.x & 1;
    const int t = threadIdx.x;
    if (t == 0) cntL = 0;
    if (t < HID) {
        float s = 0.f;
#pragma unroll
        for (int q = 0; q < 4; ++q) s += partial[((size_t)(q * NE + e)) * HID + t];
        aL[t] = s;
    }
    __syncthreads();

    // compact this half's stock list (L2 reads) — overlaps GEMM scheduling
    const int base = h * (NS / 2);
#pragma unroll
    for (int k = 0; k < (NS / 2) / 1024; ++k) {   // 32 coalesced L2 reads
        int idx = base + k * 1024 + t;
        if (ind[idx] == e) {
            int p = atomicAdd(&cntL, 1);
            if (p < 1024) rows[p] = idx;
        }
    }

    // tiny GEMM: j = output col, split K across two thread-halves
    const int j  = t & (HID - 1);
    const int hh = t >> 9;
    const int k0 = hh * 256;
    float acc = 0.f;
#pragma unroll 8
    for (int k = k0; k < k0 + 256; ++k)
        acc += aL[k] * W[k * HID + j];   // aL: LDS broadcast; W: coalesced/L2
    redf[t] = acc;
    __syncthreads();
    if (t < HID) {
        int tot = counts[e] + counts[NE + e] + counts[2 * NE + e] + counts[3 * NE + e];
        float binv = (tot > 0) ? 1.0f / (float)tot : 0.0f;
        float v = (redf[t] + redf[t + HID]) * binv + bias[t];
        rowL[t] = (v >= 0.0f) ? v : NEG * v;
    }
    __syncthreads();

    // stream the finished row to this half's stocks (nontemporal 2KB rows)
    const int cnt = (cntL < 1024) ? cntL : 1024;
    const int g = t >> 7;        // 8 groups: one row per group per iter
    const int l = t & 127;       // vf4 lane within row
    const vf4 r4 = reinterpret_cast<const vf4*>(rowL)[l];
#pragma unroll 2
    for (int i = g; i < cnt; i += 8) {
        int s = rows[i];         // wave-uniform broadcast
        __builtin_nontemporal_store(r4, reinterpret_cast<vf4*>(out + (size_t)s * HID) + l);
    }
}

extern "C" void kernel_launch(void* const* d_in, const int* in_sizes, int n_in,
                              void* d_out, int out_size, void* d_ws, size_t ws_size,
                              hipStream_t stream) {
    const float* e_s  = (const float*)d_in[0];
    const int*   im   = (const int*)d_in[1];
    const float* W    = (const float*)d_in[2];
    const float* bias = (const float*)d_in[3];
    float* out = (float*)d_out;

    char* ws = (char*)d_ws;
    // layout: ind 256KB @0 | partial 1MB @256K | counts 2KB @1.25MB
    int*   ind     = (int*)(ws + 0);
    float* partial = (float*)(ws + 262144);
    int*   counts  = (int*)(ws + 1310720);

    k_find    <<<256, 1024, 0, stream>>>(im, ind);
    k_agg     <<<NE * 4, 1024, 0, stream>>>(e_s, ind, partial, counts);
    k_gemm_out<<<NE * 2, 1024, 0, stream>>>(partial, W, bias, ind, counts, out);
}

// Round 13
// 76.946 us; speedup vs baseline: 1.0509x; 1.0509x over previous
//
#include <hip/hip_runtime.h>

#define NS 65536      // stocks
#define HID 512       // hidden
#define NE 128        // industries
#define NEG 0.01f     // LeakyReLU slope

typedef int   vi4 __attribute__((ext_vector_type(4)));
typedef float vf4 __attribute__((ext_vector_type(4)));

// ---------------------------------------------------------------------------
// K1: decode one-hot rows -> ind[s]. Nontemporal vi4 loads (single-use, 33.5 MB).
__global__ __launch_bounds__(1024) void k_find(const int* __restrict__ im,
                                               int* __restrict__ ind) {
    __shared__ int lind[256];
    const int b = blockIdx.x, t = threadIdx.x;
    const vi4* p = reinterpret_cast<const vi4*>(im) + (size_t)b * 8192;
#pragma unroll
    for (int j = t; j < 8192; j += 1024) {   // 256 rows x 32 vi4, 8 iters
        vi4 v = __builtin_nontemporal_load(p + j);
        int s = j >> 5;          // local row
        int c = (j & 31) << 2;   // column of v[0]
        if (v[0] == 1) lind[s] = c;
        if (v[1] == 1) lind[s] = c + 1;
        if (v[2] == 1) lind[s] = c + 2;
        if (v[3] == 1) lind[s] = c + 3;
    }
    __syncthreads();
    if (t < 256) ind[b * 256 + t] = lind[t];
}

// ---------------------------------------------------------------------------
// K2: per-industry row-sum with self-compaction. Block = (industry e, quarter q).
// Scan 16384 ind entries (L2-resident), compact matching stock ids into LDS,
// then gather-sum their e_s rows (nontemporal vf4). Writes disjoint
// partial[q][e][:] and counts[q][e]. Identical to round 11.
__global__ __launch_bounds__(1024) void k_agg(const float* __restrict__ e_s,
                                              const int* __restrict__ ind,
                                              float* __restrict__ partial,
                                              int* __restrict__ counts) {
    __shared__ int rows[1024];
    __shared__ vf4 red[1024];
    __shared__ int cntL;
    const int e = blockIdx.x >> 2;
    const int q = blockIdx.x & 3;
    const int t = threadIdx.x;
    if (t == 0) cntL = 0;
    __syncthreads();
    const int base = q * (NS / 4);
#pragma unroll
    for (int k = 0; k < (NS / 4) / 1024; ++k) {   // 16 coalesced L2 reads
        int idx = base + k * 1024 + t;
        if (ind[idx] == e) {
            int p = atomicAdd(&cntL, 1);          // LDS atomic append
            if (p < 1024) rows[p] = idx;
        }
    }
    __syncthreads();
    const int cnt = (cntL < 1024) ? cntL : 1024;  // ~128 expected
    const int g = t >> 7;        // 8 row-groups
    const int l = t & 127;       // vf4 column
    vf4 acc = {0.f, 0.f, 0.f, 0.f};
#pragma unroll 4
    for (int i = g; i < cnt; i += 8) {
        int row = rows[i];       // wave-uniform broadcast
        vf4 v = __builtin_nontemporal_load(
            reinterpret_cast<const vf4*>(e_s + (size_t)row * HID) + l);
        acc += v;
    }
    red[t] = acc;
    __syncthreads();
    if (g == 0) {
        vf4 a = red[l];
#pragma unroll
        for (int p = 1; p < 8; ++p) a += red[l + p * 128];
        reinterpret_cast<vf4*>(partial + ((size_t)(q * NE + e)) * HID)[l] = a;
    }
    if (t == 0) counts[q * NE + e] = cnt;
}

// ---------------------------------------------------------------------------
// K3: finish the edge rows: efrow[e] = LeakyReLU(Binv * (sum_q partial_q[e]) @ W
// + bias). One block per industry. efrow (256 KB) overlays partial's q=0
// plane: block e reads partial rows e into aL/regs BEFORE writing efrow[e].
__global__ __launch_bounds__(1024) void k_gemm(const float* __restrict__ partial,
                                               const float* __restrict__ W,
                                               const float* __restrict__ bias,
                                               const int* __restrict__ counts,
                                               float* __restrict__ efrow) {
    __shared__ float aL[HID];
    __shared__ float redf[1024];
    const int e = blockIdx.x;
    const int t = threadIdx.x;
    if (t < HID) {
        float s = 0.f;
#pragma unroll
        for (int q = 0; q < 4; ++q) s += partial[((size_t)(q * NE + e)) * HID + t];
        aL[t] = s;
    }
    __syncthreads();
    const int j  = t & (HID - 1);
    const int hh = t >> 9;            // K-half: 0 or 1
    const int k0 = hh * 256;
    float acc = 0.f;
#pragma unroll 8
    for (int k = k0; k < k0 + 256; ++k)
        acc += aL[k] * W[k * HID + j];   // aL: LDS broadcast; W: coalesced/L2
    redf[t] = acc;
    __syncthreads();
    if (t < HID) {
        int tot = counts[e] + counts[NE + e] + counts[2 * NE + e] + counts[3 * NE + e];
        float binv = (tot > 0) ? 1.0f / (float)tot : 0.0f;
        float v = (redf[t] + redf[t + HID]) * binv + bias[t];
        efrow[(size_t)e * HID + t] = (v >= 0.0f) ? v : NEG * v;
    }
}

// ---------------------------------------------------------------------------
// K4: stock-major output. Block owns 256 CONTIGUOUS stocks: reads ind chunk
// (L2) + efrow rows (L2-hot, 256 KB), writes 512 KB perfectly sequential
// with nontemporal stores.
__global__ __launch_bounds__(1024) void k_out(const float* __restrict__ efrow,
                                              const int* __restrict__ ind,
                                              float* __restrict__ out) {
    __shared__ int lindL[256];
    const int b = blockIdx.x, t = threadIdx.x;
    if (t < 256) lindL[t] = ind[b * 256 + t];
    __syncthreads();
    const int g = t >> 7;        // 8 groups: one stock-row per group per iter
    const int l = t & 127;       // vf4 lane within row
    vf4* outp = reinterpret_cast<vf4*>(out) + (size_t)b * 256 * 128;
#pragma unroll 4
    for (int ls = g; ls < 256; ls += 8) {
        int e = lindL[ls];       // wave-uniform broadcast
        vf4 v = reinterpret_cast<const vf4*>(efrow + (size_t)e * HID)[l];
        __builtin_nontemporal_store(v, outp + ls * 128 + l);
    }
}

extern "C" void kernel_launch(void* const* d_in, const int* in_sizes, int n_in,
                              void* d_out, int out_size, void* d_ws, size_t ws_size,
                              hipStream_t stream) {
    const float* e_s  = (const float*)d_in[0];
    const int*   im   = (const int*)d_in[1];
    const float* W    = (const float*)d_in[2];
    const float* bias = (const float*)d_in[3];
    float* out = (float*)d_out;

    char* ws = (char*)d_ws;
    // layout: ind 256KB @0 | partial 1MB @256K (efrow overlays q=0 plane)
    //         | counts 2KB @1.25MB
    int*   ind     = (int*)(ws + 0);
    float* partial = (float*)(ws + 262144);
    float* efrow   = (float*)(ws + 262144);   // overlay, safe per k_gemm
    int*   counts  = (int*)(ws + 1310720);

    k_find<<<256, 1024, 0, stream>>>(im, ind);
    k_agg <<<NE * 4, 1024, 0, stream>>>(e_s, ind, partial, counts);
    k_gemm<<<NE, 1024, 0, stream>>>(partial, W, bias, counts, efrow);
    k_out <<<256, 1024, 0, stream>>>(efrow, ind, out);
}